// Round 10
// baseline (186.204 us; speedup 1.0000x reference)
//
#include <hip/hip_runtime.h>
#include <math.h>

// CFE hydrologic scan (R10): 2-wave split -- use a second SIMD per CU.
// R9 (1 wave/CU, NCH=2 packed): 512 cyc/step = ~343 issue + ~170 stall.
// R10 splits the 16 m-chains of each basin across TWO waves (m0-7 / m8-15):
//  - 512 waves = 2 waves/CU on 2 different SIMDs; per-wave issue halves
//  - each wave convolves its own 8-chain partial (conv is linear); the two
//    per-basin partials are summed via a 128B parity-double-buffered LDS
//    exchange + one __syncthreads()/step, pipelined 1 step behind
//  - keeps R8/R9 wins: 15-step static ring (zero shift movs), double-buffered
//    forcing loads, DPP8 reduction, scalar chain (NCH=1 -> no packing partner)

constexpr int T_STEPS = 730;
constexpr int BATCH   = 2048;
constexpr int NMULC   = 16;
constexpr int LENFC   = 15;
constexpr int NPHYS   = 13;
constexpr int NSTAT   = NPHYS * NMULC + 2; // 210
constexpr float NZ    = 1e-5f;
constexpr float INV_NZ= 1e5f;
constexpr int BPB     = 8;                 // basins per block
constexpr int TB      = 15;                // steps per unrolled block
constexpr int T_MAIN  = 720;               // 24 x 30; tail = 10

__device__ __forceinline__ float frcp(float x) { return __builtin_amdgcn_rcpf(x); }

// 8-lane group sum via DPP (quad_perm xor1, xor2, row_half_mirror).
__device__ __forceinline__ float dpp_sum8(float x) {
    int v;
    v = __builtin_amdgcn_update_dpp(0, __float_as_int(x), 0xB1, 0xF, 0xF, true);  // quad_perm(1,0,3,2)
    x += __int_as_float(v);
    v = __builtin_amdgcn_update_dpp(0, __float_as_int(x), 0x4E, 0xF, 0xF, true);  // quad_perm(2,3,0,1)
    x += __int_as_float(v);
    v = __builtin_amdgcn_update_dpp(0, __float_as_int(x), 0x141, 0xF, 0xF, true); // row_half_mirror
    x += __int_as_float(v);
    return x;
}

struct Prm {
    float k1, k2, ms, fc, ic, cc, pc, lc, sc, e2, Km, Kk, Cg, ig;
    float w[LENFC];
};
struct St { float soil, gw, n0, n1, n2; };

// One timestep; SLOT = t % 15 (compile-time -> static ring indices).
template <int SLOT>
__device__ __forceinline__ float substep(const Prm& P, St& S,
                                         float (&ring)[LENFC], const float2 fv)
{
    const float p = fv.x, pet = fv.y;
    const float et      = fminf(p, pet);
    const float p_rem   = p - et;
    const float pet_rem = pet - et;
    const float prem_nz = p_rem + NZ;
    const float prem_sq = p_rem * p_rem;

    float budyko = fmaf(S.soil, P.k1, P.k2);
    budyko = fminf(fmaxf(budyko, 0.0f), 1.0f);
    const float aet = fminf(pet_rem * budyko, S.soil - NZ);
    float so = S.soil - aet;

    const float deficit = P.ms - so;
    const float den     = fmaf(deficit, P.ic, prem_nz);
    const float runoff0 = prem_sq * frcp(den);
    const float infil   = fminf(p_rem - runoff0, deficit);
    const float runoff  = p_rem - infil;
    so += infil;

    const float above = fmaxf(so - P.fc, 0.0f);
    const float asc   = fminf(above * P.sc, above * above * INV_NZ);
    const float lat   = P.lc * asc;
    so = fmaf(-P.cc, asc, so);
    S.soil = so;

    float g = fmaf(P.pc, asc, S.gw);
    const float ratio = fminf(g * P.ig, 1.0f);
    const float qg0   = fmaf(P.Cg, __builtin_amdgcn_exp2f(P.e2 * ratio), -P.Cg);
    const float qg    = fminf(qg0, g - NZ);
    S.gw = g - qg;

    const float s0 = S.n0 + lat;            const float s1 = fmaf(P.Kk, s0, S.n1);
    const float s2 = fmaf(P.Kk, s1, S.n2);  const float o2 = P.Kk * s2;
    S.n0 = P.Km * s0; S.n1 = P.Km * s1; S.n2 = P.Km * s2;

    const float qsum = runoff + o2 + qg;

    ring[SLOT] = qsum;
    float c0 = 0.0f, c1 = 0.0f, c2 = 0.0f, c3 = 0.0f;
    #pragma unroll
    for (int j = 0; j < LENFC; j += 4) {
        c0 = fmaf(P.w[j], ring[(SLOT - j + 15) % 15], c0);
        if (j + 1 < LENFC) c1 = fmaf(P.w[j + 1], ring[(SLOT - j - 1 + 30) % 15], c1);
        if (j + 2 < LENFC) c2 = fmaf(P.w[j + 2], ring[(SLOT - j - 2 + 30) % 15], c2);
        if (j + 3 < LENFC) c3 = fmaf(P.w[j + 3], ring[(SLOT - j - 3 + 30) % 15], c3);
    }
    return (c0 + c1) + (c2 + c3);
}

// Per step: publish r_{t-1} (parity-double-buffered), barrier, wave0 stores
// the cross-wave sum, then run the chain for step t. tb is always even here
// (steps by 30), so parity = s&1 is compile-time.
#define SUBST(s, FBUF, TBASE) {                                                 \
    const float r = dpp_sum8(s_prev);                                           \
    if (red0) smx[(s) & 1][wv * BPB + bb] = r;                                  \
    __syncthreads();                                                            \
    if (st0 && ((TBASE) + (s)) > 0)                                             \
        out[((TBASE) + (s) - 1) * BATCH + b] =                                  \
            smx[(s) & 1][bb] + smx[(s) & 1][BPB + bb];                          \
    s_prev = substep<(s)>(P, S, ring, FBUF[(s)]); }
#define DO15(FBUF, TBASE) \
    SUBST(0,FBUF,TBASE) SUBST(1,FBUF,TBASE) SUBST(2,FBUF,TBASE)  \
    SUBST(3,FBUF,TBASE) SUBST(4,FBUF,TBASE) SUBST(5,FBUF,TBASE)  \
    SUBST(6,FBUF,TBASE) SUBST(7,FBUF,TBASE) SUBST(8,FBUF,TBASE)  \
    SUBST(9,FBUF,TBASE) SUBST(10,FBUF,TBASE) SUBST(11,FBUF,TBASE)\
    SUBST(12,FBUF,TBASE) SUBST(13,FBUF,TBASE) SUBST(14,FBUF,TBASE)
#define DO10(FBUF, TBASE) \
    SUBST(0,FBUF,TBASE) SUBST(1,FBUF,TBASE) SUBST(2,FBUF,TBASE)  \
    SUBST(3,FBUF,TBASE) SUBST(4,FBUF,TBASE) SUBST(5,FBUF,TBASE)  \
    SUBST(6,FBUF,TBASE) SUBST(7,FBUF,TBASE) SUBST(8,FBUF,TBASE)  \
    SUBST(9,FBUF,TBASE)

__global__ __launch_bounds__(128, 1)
void cfe_kernel(const float* __restrict__ x,   // (T,B,2)
                const float* __restrict__ ps,  // (B,NSTAT)
                float* __restrict__ out)       // (T,B)
{
    __shared__ float smx[2][2 * BPB];          // parity x (wave,basin)

    const int lt   = threadIdx.x;              // 0..127
    const int lane = lt & 63;
    const int wv   = lt >> 6;                  // 0 or 1
    const int bb   = lane >> 3;                // basin in block
    const int b    = blockIdx.x * BPB + bb;
    const int m    = (lane & 7) + wv * 8;      // this thread's m-chain
    const bool red0 = ((lane & 7) == 0);
    const bool st0  = red0 && (wv == 0);

    const float* __restrict__ row = ps + b * NSTAT;

    Prm P;
    {
        const float schaake    = row[ 0*NMULC + m] * 0.1f;
        const float smcmax     = row[ 1*NMULC + m] * 0.3f   + 0.3f;
        const float soil_depth = row[ 2*NMULC + m] * 2.5f   + 0.5f;
        const float wltsmc     = row[ 3*NMULC + m] * 0.15f  + 0.05f;
        const float satpsi     = row[ 4*NMULC + m] * 0.49f  + 0.01f;
        const float bb_        = row[ 5*NMULC + m] * 10.0f  + 2.0f;
        const float multp      = row[ 6*NMULC + m] * 1900.0f+ 100.0f;
        const float satdk      = row[ 7*NMULC + m] * (1e-4f - 1e-7f) + 1e-7f;
        const float slop       = row[ 8*NMULC + m];
        const float max_gw     = row[ 9*NMULC + m] * 0.49f  + 0.01f;
        const float Cgw        = row[10*NMULC + m] * (1e-3f - 1e-6f) + 1e-6f;
        const float expon      = row[11*NMULC + m] * 7.0f   + 1.0f;
        const float K          = row[12*NMULC + m] * 0.49f  + 0.01f;

        const float inv_sd  = 1.0f / soil_depth;
        const float bud_den = 1.0f / (smcmax - wltsmc + NZ);
        const float ms      = smcmax * soil_depth;
        float fc_frac = powf(satpsi * inv_sd, 1.0f / bb_);
        fc_frac = fminf(fmaxf(fc_frac, 0.0f), 1.0f);
        const float fc      = smcmax * fc_frac * soil_depth;
        const float sm      = satdk * multp;
        const float sml     = sm * slop;
        const float inv_mft = 1.0f / fmaxf(ms - fc, NZ);
        const float ccv     = inv_mft * (sm + sml);

        P.k1 = inv_sd * bud_den;
        P.k2 = -wltsmc * bud_den;
        P.ms = ms;
        P.fc = fc;
        P.ic = 1.0f - expf(-schaake);
        P.cc = ccv;
        P.pc = sm  * inv_mft;
        P.lc = sml * inv_mft;
        P.sc = fminf(1.0f, 1.0f / ccv);
        P.e2 = expon * 1.442695041f;        // expon * log2(e)
        P.Km = 1.0f - K;
        P.Kk = K;
        P.Cg = Cgw;
        P.ig = 1.0f / max_gw;
    }

    // routing weights: per-basin (both waves compute identically)
    {
        const float rout_a = row[NPHYS*NMULC + 0] * 2.9f;
        const float rout_b = row[NPHYS*NMULC + 1] * 6.5f;
        const float a  = fmaxf(rout_a, 0.0f) + 0.1f;
        const float th = fmaxf(rout_b, 0.0f) + 0.5f;
        float wsum = 0.0f;
        #pragma unroll
        for (int j = 0; j < LENFC; ++j) {
            const float tj = (float)j + 0.5f;
            P.w[j] = powf(tj, a - 1.0f) * expf(-tj / th);
            wsum += P.w[j];
        }
        const float wscale = 1.0f / (wsum * (float)NMULC);
        #pragma unroll
        for (int j = 0; j < LENFC; ++j) P.w[j] *= wscale;
    }

    St S;
    S.soil = 0.05f; S.gw = 0.01f; S.n0 = NZ; S.n1 = NZ; S.n2 = NZ;
    float ring[LENFC];
    #pragma unroll
    for (int j = 0; j < LENFC; ++j) ring[j] = 0.0f;

    const float2* __restrict__ xp = (const float2*)x;

    // forcing double-buffer (15 steps each)
    float2 fA[TB], fB[TB];
    #pragma unroll
    for (int s = 0; s < TB; ++s) fA[s] = xp[s * BATCH + b];

    float s_prev = 0.0f;

    #pragma unroll 1
    for (int tb = 0; tb < T_MAIN; tb += 2 * TB) {
        #pragma unroll
        for (int s = 0; s < TB; ++s) {
            int t = tb + TB + s; if (t > T_STEPS - 1) t = T_STEPS - 1;
            fB[s] = xp[t * BATCH + b];
        }
        DO15(fA, tb)
        #pragma unroll
        for (int s = 0; s < TB; ++s) {
            int t = tb + 2 * TB + s; if (t > T_STEPS - 1) t = T_STEPS - 1;
            fA[s] = xp[t * BATCH + b];
        }
        DO15(fB, tb + TB)
    }

    // tail: 10 steps (720..729); fA holds them (clamped loads)
    DO10(fA, T_MAIN)

    // epilogue: publish + store the final step (parity 10&1 = 0)
    {
        const float r = dpp_sum8(s_prev);
        if (red0) smx[0][wv * BPB + bb] = r;
        __syncthreads();
        if (st0) out[(T_STEPS - 1) * BATCH + b] = smx[0][bb] + smx[0][BPB + bb];
    }
}

extern "C" void kernel_launch(void* const* d_in, const int* in_sizes, int n_in,
                              void* d_out, int out_size, void* d_ws, size_t ws_size,
                              hipStream_t stream) {
    const float* x_phy      = (const float*)d_in[0];
    const float* phy_static = (const float*)d_in[1];
    float* out = (float*)d_out;

    const int grid = BATCH / BPB;               // 256 blocks -> 1 per CU
    cfe_kernel<<<grid, 128, 0, stream>>>(x_phy, phy_static, out);
}

// Round 11
// 154.300 us; speedup vs baseline: 1.2068x; 1.2068x over previous
//
#include <hip/hip_runtime.h>
#include <math.h>

// CFE hydrologic scan (R11): R9 + provable critical-path shaves.
// R10 post-mortem: cross-wave per-step cooperation costs ~250 cyc/step in
// barrier/LDS-visibility overhead -> dead. R9 config (NCH=2 packed chains,
// 8 lanes/basin, 256 waves = 1/CU) is the measured Pareto point.
// R11 shaves the serial dependency path:
//  (1) drop min(budyko,1): soil<=max_soil => budyko<1 ALWAYS (proof in-line)
//  (2) fold e2 into ig: exp2(e2*min(g*ig,1)) == exp2(min(g*(ig*e2), e2))
// Everything else bit-identical to R9.

constexpr int T_STEPS = 730;
constexpr int BATCH   = 2048;
constexpr int NMULC   = 16;
constexpr int LENFC   = 15;
constexpr int NPHYS   = 13;
constexpr int NSTAT   = NPHYS * NMULC + 2; // 210
constexpr float NZ    = 1e-5f;
constexpr float INV_NZ= 1e5f;
constexpr int NCH     = 2;                 // m-chains per thread (packed)
constexpr int LPB     = 8;                 // lanes per basin
constexpr int TB      = 15;                // steps per unrolled block
constexpr int T_MAIN  = 720;               // 24 x 30; tail = 10

typedef float v2f __attribute__((ext_vector_type(2)));

__device__ __forceinline__ float frcp(float x) { return __builtin_amdgcn_rcpf(x); }
__device__ __forceinline__ v2f v2(float s) { return (v2f){s, s}; }
__device__ __forceinline__ v2f vmin(v2f a, v2f b) { return __builtin_elementwise_min(a, b); }
__device__ __forceinline__ v2f vmax(v2f a, v2f b) { return __builtin_elementwise_max(a, b); }

// 8-lane group sum via DPP (quad_perm xor1, xor2, row_half_mirror).
__device__ __forceinline__ float dpp_sum8(float x) {
    int v;
    v = __builtin_amdgcn_update_dpp(0, __float_as_int(x), 0xB1, 0xF, 0xF, true);  // quad_perm(1,0,3,2)
    x += __int_as_float(v);
    v = __builtin_amdgcn_update_dpp(0, __float_as_int(x), 0x4E, 0xF, 0xF, true);  // quad_perm(2,3,0,1)
    x += __int_as_float(v);
    v = __builtin_amdgcn_update_dpp(0, __float_as_int(x), 0x141, 0xF, 0xF, true); // row_half_mirror
    x += __int_as_float(v);
    return x;
}

struct Prm {
    v2f k1, k2, ms, fc, ic, cc, pc, lc, sc, e2, Km, Kk, Cg, ige2;
    float w[LENFC];
};
struct St { v2f soil, gw, n0, n1, n2; };

// One timestep; SLOT = t % 15 (compile-time -> static ring indices).
template <int SLOT>
__device__ __forceinline__ float substep(const Prm& P, St& S,
                                         float (&ring)[LENFC], const float2 fv)
{
    const float p = fv.x, pet = fv.y;
    const float et      = fminf(p, pet);
    const float p_rem   = p - et;
    const float pet_rem = pet - et;
    const float prem_nz = p_rem + NZ;
    const float prem_sq = p_rem * p_rem;

    // -- both chains as one packed stream --------------------------------
    // budyko < 1 always: soil <= ms => smc <= smcmax =>
    // (smc-wlt)*bud_den <= (smcmax-wlt)/(smcmax-wlt+NZ) < 1  -> no min(,1)
    v2f budyko = S.soil * P.k1 + P.k2;                       // pk_fma
    budyko = vmax(budyko, v2(0.0f));
    const v2f aet = vmin(v2(pet_rem) * budyko, S.soil - v2(NZ));
    v2f so = S.soil - aet;

    const v2f deficit = P.ms - so;
    const v2f den     = deficit * P.ic + v2(prem_nz);        // pk_fma
    v2f rden; rden.x = frcp(den.x); rden.y = frcp(den.y);
    const v2f runoff0 = v2(prem_sq) * rden;
    const v2f infil   = vmin(v2(p_rem) - runoff0, deficit);
    const v2f runoff  = v2(p_rem) - infil;
    so += infil;

    const v2f above = vmax(so - P.fc, v2(0.0f));
    const v2f asc   = vmin(above * P.sc, above * above * v2(INV_NZ));
    const v2f lat   = P.lc * asc;
    so = so - P.cc * asc;                                    // pk_fma (neg)
    S.soil = so;

    v2f g = P.pc * asc + S.gw;                               // pk_fma
    // folded: exp2(e2 * min(g*ig, 1)) == exp2(min(g*(ig*e2), e2))
    const v2f xin = vmin(g * P.ige2, P.e2);
    v2f ex;
    ex.x = __builtin_amdgcn_exp2f(xin.x);
    ex.y = __builtin_amdgcn_exp2f(xin.y);
    const v2f qg0 = P.Cg * ex - P.Cg;                        // pk_fma
    const v2f qg  = vmin(qg0, g - v2(NZ));
    S.gw = g - qg;

    const v2f s0 = S.n0 + lat;
    const v2f s1 = P.Kk * s0 + S.n1;                         // pk_fma
    const v2f s2 = P.Kk * s1 + S.n2;                         // pk_fma
    const v2f o2 = P.Kk * s2;
    S.n0 = P.Km * s0; S.n1 = P.Km * s1; S.n2 = P.Km * s2;

    const v2f qv = runoff + o2 + qg;
    const float qsum = qv.x + qv.y;

    ring[SLOT] = qsum;
    float c0 = 0.0f, c1 = 0.0f, c2 = 0.0f, c3 = 0.0f;
    #pragma unroll
    for (int j = 0; j < LENFC; j += 4) {
        c0 = fmaf(P.w[j], ring[(SLOT - j + 15) % 15], c0);
        if (j + 1 < LENFC) c1 = fmaf(P.w[j + 1], ring[(SLOT - j - 1 + 30) % 15], c1);
        if (j + 2 < LENFC) c2 = fmaf(P.w[j + 2], ring[(SLOT - j - 2 + 30) % 15], c2);
        if (j + 3 < LENFC) c3 = fmaf(P.w[j + 3], ring[(SLOT - j - 3 + 30) % 15], c3);
    }
    return (c0 + c1) + (c2 + c3);
}

#define SUBST(s, FBUF, TBASE) {                                              \
    const float acc = substep<(s)>(P, S, ring, FBUF[(s)]);                   \
    const float r = dpp_sum8(acc);                                           \
    if (lane0) out[((TBASE) + (s)) * BATCH + b] = r; }
#define DO15(FBUF, TBASE) \
    SUBST(0,FBUF,TBASE) SUBST(1,FBUF,TBASE) SUBST(2,FBUF,TBASE)  \
    SUBST(3,FBUF,TBASE) SUBST(4,FBUF,TBASE) SUBST(5,FBUF,TBASE)  \
    SUBST(6,FBUF,TBASE) SUBST(7,FBUF,TBASE) SUBST(8,FBUF,TBASE)  \
    SUBST(9,FBUF,TBASE) SUBST(10,FBUF,TBASE) SUBST(11,FBUF,TBASE)\
    SUBST(12,FBUF,TBASE) SUBST(13,FBUF,TBASE) SUBST(14,FBUF,TBASE)
#define DO10(FBUF, TBASE) \
    SUBST(0,FBUF,TBASE) SUBST(1,FBUF,TBASE) SUBST(2,FBUF,TBASE)  \
    SUBST(3,FBUF,TBASE) SUBST(4,FBUF,TBASE) SUBST(5,FBUF,TBASE)  \
    SUBST(6,FBUF,TBASE) SUBST(7,FBUF,TBASE) SUBST(8,FBUF,TBASE)  \
    SUBST(9,FBUF,TBASE)

__global__ __launch_bounds__(64, 1)
void cfe_kernel(const float* __restrict__ x,   // (T,B,2)
                const float* __restrict__ ps,  // (B,NSTAT)
                float* __restrict__ out)       // (T,B)
{
    const int tid = blockIdx.x * 64 + threadIdx.x;
    const int b   = tid >> 3;     // basin
    const int m0  = tid & 7;      // handles m0 and m0+8
    const bool lane0 = (m0 == 0);

    const float* __restrict__ row = ps + b * NSTAT;

    Prm P;
    #pragma unroll
    for (int c = 0; c < NCH; ++c) {
        const int m = m0 + c * 8;
        const float schaake    = row[ 0*NMULC + m] * 0.1f;
        const float smcmax     = row[ 1*NMULC + m] * 0.3f   + 0.3f;
        const float soil_depth = row[ 2*NMULC + m] * 2.5f   + 0.5f;
        const float wltsmc     = row[ 3*NMULC + m] * 0.15f  + 0.05f;
        const float satpsi     = row[ 4*NMULC + m] * 0.49f  + 0.01f;
        const float bb_        = row[ 5*NMULC + m] * 10.0f  + 2.0f;
        const float multp      = row[ 6*NMULC + m] * 1900.0f+ 100.0f;
        const float satdk      = row[ 7*NMULC + m] * (1e-4f - 1e-7f) + 1e-7f;
        const float slop       = row[ 8*NMULC + m];
        const float max_gw     = row[ 9*NMULC + m] * 0.49f  + 0.01f;
        const float Cgw        = row[10*NMULC + m] * (1e-3f - 1e-6f) + 1e-6f;
        const float expon      = row[11*NMULC + m] * 7.0f   + 1.0f;
        const float K          = row[12*NMULC + m] * 0.49f  + 0.01f;

        const float inv_sd  = 1.0f / soil_depth;
        const float bud_den = 1.0f / (smcmax - wltsmc + NZ);
        const float ms      = smcmax * soil_depth;
        float fc_frac = powf(satpsi * inv_sd, 1.0f / bb_);
        fc_frac = fminf(fmaxf(fc_frac, 0.0f), 1.0f);
        const float fc      = smcmax * fc_frac * soil_depth;
        const float sm      = satdk * multp;
        const float sml     = sm * slop;
        const float inv_mft = 1.0f / fmaxf(ms - fc, NZ);
        const float ccv     = inv_mft * (sm + sml);
        const float e2v     = expon * 1.442695041f;   // expon * log2(e)
        const float igv     = 1.0f / max_gw;

        P.k1[c] = inv_sd * bud_den;
        P.k2[c] = -wltsmc * bud_den;
        P.ms[c] = ms;
        P.fc[c] = fc;
        P.ic[c] = 1.0f - expf(-schaake);
        P.cc[c] = ccv;
        P.pc[c] = sm  * inv_mft;
        P.lc[c] = sml * inv_mft;
        P.sc[c] = fminf(1.0f, 1.0f / ccv);
        P.e2[c] = e2v;
        P.Km[c] = 1.0f - K;
        P.Kk[c] = K;
        P.Cg[c] = Cgw;
        P.ige2[c] = igv * e2v;
    }

    // routing weights: per-basin, shared by both chains
    {
        const float rout_a = row[NPHYS*NMULC + 0] * 2.9f;
        const float rout_b = row[NPHYS*NMULC + 1] * 6.5f;
        const float a  = fmaxf(rout_a, 0.0f) + 0.1f;
        const float th = fmaxf(rout_b, 0.0f) + 0.5f;
        float wsum = 0.0f;
        #pragma unroll
        for (int j = 0; j < LENFC; ++j) {
            const float tj = (float)j + 0.5f;
            P.w[j] = powf(tj, a - 1.0f) * expf(-tj / th);
            wsum += P.w[j];
        }
        const float wscale = 1.0f / (wsum * (float)NMULC);
        #pragma unroll
        for (int j = 0; j < LENFC; ++j) P.w[j] *= wscale;
    }

    St S;
    S.soil = v2(0.05f); S.gw = v2(0.01f);
    S.n0 = v2(NZ); S.n1 = v2(NZ); S.n2 = v2(NZ);
    float ring[LENFC];
    #pragma unroll
    for (int j = 0; j < LENFC; ++j) ring[j] = 0.0f;

    const float2* __restrict__ xp = (const float2*)x;

    // ---- forcing double-buffer: fA holds current block, fB prefetched ---
    float2 fA[TB], fB[TB];
    #pragma unroll
    for (int s = 0; s < TB; ++s) fA[s] = xp[s * BATCH + b];

    #pragma unroll 1
    for (int tb = 0; tb < T_MAIN; tb += 2 * TB) {
        // prefetch next block (tb+15) while computing on fA
        #pragma unroll
        for (int s = 0; s < TB; ++s) {
            int t = tb + TB + s; if (t > T_STEPS - 1) t = T_STEPS - 1;
            fB[s] = xp[t * BATCH + b];
        }
        DO15(fA, tb)
        // prefetch block tb+30 while computing on fB
        #pragma unroll
        for (int s = 0; s < TB; ++s) {
            int t = tb + 2 * TB + s; if (t > T_STEPS - 1) t = T_STEPS - 1;
            fA[s] = xp[t * BATCH + b];
        }
        DO15(fB, tb + TB)
    }

    // ---- tail: 10 steps (720..729); fA already holds them (clamped load)
    DO10(fA, T_MAIN)
}

extern "C" void kernel_launch(void* const* d_in, const int* in_sizes, int n_in,
                              void* d_out, int out_size, void* d_ws, size_t ws_size,
                              hipStream_t stream) {
    const float* x_phy      = (const float*)d_in[0];
    const float* phy_static = (const float*)d_in[1];
    float* out = (float*)d_out;

    const int total = BATCH * LPB;              // 16384 threads
    const int block = 64;
    const int grid  = total / block;            // 256 blocks -> 1 per CU
    cfe_kernel<<<grid, block, 0, stream>>>(x_phy, phy_static, out);
}